// Round 7
// baseline (115.880 us; speedup 1.0000x reference)
//
#include <hip/hip_runtime.h>
#include <hip/hip_bf16.h>

typedef short bf16x8 __attribute__((ext_vector_type(8)));
typedef float f32x4 __attribute__((ext_vector_type(4)));

constexpr int Nn = 65536;
constexpr int Kk = 256;
constexpr int Dd = 512;
constexpr int BM = 32;               // rows per block
constexpr int BK = 64;               // k per phase
constexpr int NPH = Dd / BK;         // 8 phases
constexpr int ATILE = BM * BK * 4;   // 8 KB fp32 A slice in LDS

static __device__ __forceinline__ unsigned short f2bf(float f) {
  __hip_bfloat16 h = __float2bfloat16(f);
  return *reinterpret_cast<unsigned short*>(&h);
}

static __device__ __forceinline__ bf16x8 pack8(float4 u, float4 v) {
  union { unsigned u32[4]; bf16x8 v8; } r;
  r.u32[0] = ((unsigned)f2bf(u.y) << 16) | f2bf(u.x);
  r.u32[1] = ((unsigned)f2bf(u.w) << 16) | f2bf(u.z);
  r.u32[2] = ((unsigned)f2bf(v.y) << 16) | f2bf(v.x);
  r.u32[3] = ((unsigned)f2bf(v.w) << 16) | f2bf(v.z);
  return r.v8;
}

// LDS-visibility-only barrier: vmcnt NOT drained (prefetches stay in flight).
static __device__ __forceinline__ void rbar() {
  asm volatile("s_waitcnt lgkmcnt(0)" ::: "memory");
  __builtin_amdgcn_s_barrier();
  asm volatile("" ::: "memory");
}
// Compiler-level fence: orders the IR memory ops (keeps gloadA before loadB so
// in-order vmcnt retirement of bB implies A landed — no counted vmcnt needed).
static __device__ __forceinline__ void fence() { asm volatile("" ::: "memory"); }

// Async 16B/lane global->LDS. LDS dest = wave-uniform base + lane*16 (linear);
// swizzle achieved by permuting the per-lane GLOBAL source (rule 21 involution).
static __device__ __forceinline__ void gload16(const float* g, void* l) {
  __builtin_amdgcn_global_load_lds(
      (const __attribute__((address_space(1))) unsigned int*)g,
      (__attribute__((address_space(3))) unsigned int*)l, 16, 0, 0);
}

// Clusters -> bf16 row-major [K][D] + c2[k] = sum_d C[k][d]^2 (fp32).
__global__ __launch_bounds__(64)
void prep_clusters_kernel(const float* __restrict__ C,
                          unsigned short* __restrict__ CB,
                          float* __restrict__ c2) {
  const int k = blockIdx.x;
  const int t = threadIdx.x;
  const float* row = C + (size_t)k * Dd;
  float4 a = *reinterpret_cast<const float4*>(row + t * 8);
  float4 b = *reinterpret_cast<const float4*>(row + t * 8 + 4);
  float s = a.x * a.x + a.y * a.y + a.z * a.z + a.w * a.w
          + b.x * b.x + b.y * b.y + b.z * b.z + b.w * b.w;
  uint4 p;
  p.x = ((unsigned)f2bf(a.y) << 16) | f2bf(a.x);
  p.y = ((unsigned)f2bf(a.w) << 16) | f2bf(a.z);
  p.z = ((unsigned)f2bf(b.y) << 16) | f2bf(b.x);
  p.w = ((unsigned)f2bf(b.w) << 16) | f2bf(b.z);
  *reinterpret_cast<uint4*>(CB + (size_t)k * Dd + t * 8) = p;
  #pragma unroll
  for (int m = 1; m < 64; m <<= 1) s += __shfl_xor(s, m, 64);
  if (t == 0) c2[k] = s;
}

// 256 threads (4 waves). Wave w owns cols [64w, 64w+64) of all BM=32 rows.
// A: fp32 via global_load_lds, triple-buffered, XOR-swizzled (source-permuted).
// B: bf16 reg double-buffer, loaded 1 phase ahead from L2-resident CB.
__global__ __launch_bounds__(256)
void cluster_q_kernel(const float* __restrict__ X,
                      const unsigned short* __restrict__ CB,
                      const float* __restrict__ c2g,
                      float* __restrict__ out) {
  __shared__ __align__(16) unsigned char Al[3][ATILE];
  __shared__ float x2s[BM];
  __shared__ float rowp[BM][4];

  const int tid  = threadIdx.x;
  const int lane = tid & 63;
  const int w    = tid >> 6;
  const int hi   = lane >> 4;   // 0..3
  const int lo   = lane & 15;   // 0..15
  const int rb   = blockIdx.x * BM;

  // --- A staging role: thread covers LDS 16B-chunks t0 and t0+64 of the 512-chunk tile.
  // Linear LDS chunk t holds global chunk (cc ^ (row&7)) of row t>>4 (XOR involution).
  const int t0 = w * 128 + lane;
  const int r0 = t0 >> 4,        r1 = (t0 + 64) >> 4;
  const int c0s = ((t0 & 15) ^ (r0 & 7)) * 4;
  const int c1s = (((t0 + 64) & 15) ^ (r1 & 7)) * 4;
  const float* src0 = X + (size_t)(rb + r0) * Dd + c0s;
  const float* src1 = X + (size_t)(rb + r1) * Dd + c1s;
  void* dst0[3]; void* dst1[3];
  #pragma unroll
  for (int b = 0; b < 3; ++b) {
    dst0[b] = &Al[b][(w * 128 + lane) * 16];
    dst1[b] = &Al[b][(w * 128 + 64 + lane) * 16];
  }

  f32x4 acc[2][4];
  #pragma unroll
  for (int m = 0; m < 2; ++m)
    #pragma unroll
    for (int n = 0; n < 4; ++n)
      #pragma unroll
      for (int r = 0; r < 4; ++r) acc[m][n][r] = 0.f;

  bf16x8 bB[2][4][2];
  float x2p[2] = {0.f, 0.f};

  auto gloadA = [&](int ks) {
    gload16(src0 + ks * BK, dst0[ks % 3]);
    gload16(src1 + ks * BK, dst1[ks % 3]);
  };
  auto loadB = [&](int ks) {
    #pragma unroll
    for (int n = 0; n < 4; ++n)
      #pragma unroll
      for (int ku = 0; ku < 2; ++ku)
        bB[ks & 1][n][ku] = *reinterpret_cast<const bf16x8*>(
            &CB[(size_t)(w * 64 + n * 16 + lo) * Dd + ks * BK + ku * 32 + hi * 8]);
  };
  auto compute = [&](int ks) {
    const unsigned char* base = Al[ks % 3];
    #pragma unroll
    for (int m = 0; m < 2; ++m) {
      const int row = m * 16 + lo;
      const int s   = row & 7;
      #pragma unroll
      for (int ku = 0; ku < 2; ++ku) {
        const int c0 = ku * 8 + hi * 2;
        float4 q0 = *reinterpret_cast<const float4*>(&base[row * 256 + ((c0 ^ s) * 16)]);
        float4 q1 = *reinterpret_cast<const float4*>(&base[row * 256 + (((c0 + 1) ^ s) * 16)]);
        x2p[m] += q0.x * q0.x + q0.y * q0.y + q0.z * q0.z + q0.w * q0.w
                + q1.x * q1.x + q1.y * q1.y + q1.z * q1.z + q1.w * q1.w;
        bf16x8 af = pack8(q0, q1);
        #pragma unroll
        for (int n = 0; n < 4; ++n)
          acc[m][n] = __builtin_amdgcn_mfma_f32_16x16x32_bf16(af, bB[ks & 1][n][ku], acc[m][n], 0, 0, 0);
      }
    }
  };

  // --- Prologue: A(0),A(1) async to LDS; B(0) to regs; force A(0)/A(1) landed.
  gloadA(0);
  gloadA(1);
  fence();
  loadB(0);
  asm volatile("s_waitcnt vmcnt(8)" ::: "memory");  // 8 B-loads may remain in flight
  __builtin_amdgcn_s_barrier();
  fence();

  #pragma unroll
  for (int ks = 0; ks < NPH; ++ks) {
    if (ks < NPH - 2) { gloadA(ks + 2); fence(); }
    if (ks < NPH - 1) loadB(ks + 1);
    compute(ks);                 // bB[ks] reg-wait also forces gloadA(ks+1) retired (in-order)
    if (ks < NPH - 1) rbar();    // lgkm-only: global prefetches stay in flight
  }

  // x2: each lane holds 16 of 64 elems per row m*16+lo; sum the 4 hi-variants.
  #pragma unroll
  for (int m = 0; m < 2; ++m) {
    float s = x2p[m];
    s += __shfl_xor(s, 16);
    s += __shfl_xor(s, 32);
    if (w == 0 && lane < 16) x2s[m * 16 + lane] = s;
  }
  __syncthreads();

  float c2v[4];
  #pragma unroll
  for (int n = 0; n < 4; ++n) c2v[n] = c2g[w * 64 + n * 16 + lo];

  // q = 1/(1+dist) (ALPHA=1) via v_rcp_f32 (q<=1: abs err ~1e-7 << 1e-4 threshold).
  float rs[2][4];
  #pragma unroll
  for (int m = 0; m < 2; ++m)
    #pragma unroll
    for (int r = 0; r < 4; ++r) rs[m][r] = 0.f;

  #pragma unroll
  for (int m = 0; m < 2; ++m) {
    #pragma unroll
    for (int r = 0; r < 4; ++r) {
      const float x2v = x2s[m * 16 + hi * 4 + r];   // C/D: col=lane&15, row=(lane>>4)*4+reg
      #pragma unroll
      for (int n = 0; n < 4; ++n) {
        float dist = fmaxf(x2v + c2v[n] - 2.f * acc[m][n][r], 0.f);
        float qv = __builtin_amdgcn_rcpf(1.f + dist);
        acc[m][n][r] = qv;
        rs[m][r] += qv;
      }
    }
  }

  // Row sums: reduce over the 16 col-lanes, then across 4 waves via LDS.
  #pragma unroll
  for (int m = 0; m < 2; ++m)
    #pragma unroll
    for (int r = 0; r < 4; ++r) {
      float s = rs[m][r];
      s += __shfl_xor(s, 1); s += __shfl_xor(s, 2);
      s += __shfl_xor(s, 4); s += __shfl_xor(s, 8);
      rs[m][r] = s;
    }
  if (lo == 0) {
    #pragma unroll
    for (int m = 0; m < 2; ++m)
      #pragma unroll
      for (int r = 0; r < 4; ++r) rowp[m * 16 + hi * 4 + r][w] = rs[m][r];
  }
  __syncthreads();

  float rinv[2][4];
  #pragma unroll
  for (int m = 0; m < 2; ++m)
    #pragma unroll
    for (int r = 0; r < 4; ++r) {
      const int row = m * 16 + hi * 4 + r;
      rinv[m][r] = __builtin_amdgcn_rcpf(rowp[row][0] + rowp[row][1] + rowp[row][2] + rowp[row][3]);
    }

  #pragma unroll
  for (int m = 0; m < 2; ++m)
    #pragma unroll
    for (int n = 0; n < 4; ++n)
      #pragma unroll
      for (int r = 0; r < 4; ++r)
        out[(size_t)(rb + m * 16 + hi * 4 + r) * Kk + w * 64 + n * 16 + lo] = acc[m][n][r] * rinv[m][r];
}

extern "C" void kernel_launch(void* const* d_in, const int* in_sizes, int n_in,
                              void* d_out, int out_size, void* d_ws, size_t ws_size,
                              hipStream_t stream) {
  const float* X = reinterpret_cast<const float*>(d_in[0]);
  const float* C = reinterpret_cast<const float*>(d_in[1]);
  unsigned short* CB = reinterpret_cast<unsigned short*>(d_ws);           // 256 KB bf16 clusters
  float* c2 = reinterpret_cast<float*>(reinterpret_cast<char*>(d_ws) + (size_t)Kk * Dd * 2);
  prep_clusters_kernel<<<Kk, 64, 0, stream>>>(C, CB, c2);
  cluster_q_kernel<<<Nn / BM, 256, 0, stream>>>(X, CB, c2, reinterpret_cast<float*>(d_out));
}

// Round 8
// 88.451 us; speedup vs baseline: 1.3101x; 1.3101x over previous
//
#include <hip/hip_runtime.h>
#include <hip/hip_bf16.h>

typedef short bf16x8 __attribute__((ext_vector_type(8)));
typedef float f32x4 __attribute__((ext_vector_type(4)));

constexpr int Nn = 65536;
constexpr int Kk = 256;
constexpr int Dd = 512;
constexpr int TROWS = 32;                 // rows per tile
constexpr int NT = 4;                     // tiles per block
constexpr int ATILE = TROWS * Dd * 4;     // 64 KB fp32 A tile

static __device__ __forceinline__ unsigned short f2bf(float f) {
  __hip_bfloat16 h = __float2bfloat16(f);
  return *reinterpret_cast<unsigned short*>(&h);
}

static __device__ __forceinline__ bf16x8 pack8(float4 u, float4 v) {
  union { unsigned u32[4]; bf16x8 v8; } r;
  r.u32[0] = ((unsigned)f2bf(u.y) << 16) | f2bf(u.x);
  r.u32[1] = ((unsigned)f2bf(u.w) << 16) | f2bf(u.z);
  r.u32[2] = ((unsigned)f2bf(v.y) << 16) | f2bf(v.x);
  r.u32[3] = ((unsigned)f2bf(v.w) << 16) | f2bf(v.z);
  return r.v8;
}

static __device__ __forceinline__ void fence() { asm volatile("" ::: "memory"); }

// LDS-visibility-only barrier: vmcnt NOT drained (in-flight staging survives).
static __device__ __forceinline__ void rbar() {
  asm volatile("s_waitcnt lgkmcnt(0)" ::: "memory");
  __builtin_amdgcn_s_barrier();
  fence();
}

static __device__ __forceinline__ void gload16(const float* g, void* l) {
  __builtin_amdgcn_global_load_lds(
      (const __attribute__((address_space(1))) unsigned int*)g,
      (__attribute__((address_space(3))) unsigned int*)l, 16, 0, 0);
}

// Clusters -> bf16 row-major [K][D] + c2[k] = sum_d C[k][d]^2 (fp32).
__global__ __launch_bounds__(64)
void prep_clusters_kernel(const float* __restrict__ C,
                          unsigned short* __restrict__ CB,
                          float* __restrict__ c2) {
  const int k = blockIdx.x;
  const int t = threadIdx.x;
  const float* row = C + (size_t)k * Dd;
  float4 a = *reinterpret_cast<const float4*>(row + t * 8);
  float4 b = *reinterpret_cast<const float4*>(row + t * 8 + 4);
  float s = a.x * a.x + a.y * a.y + a.z * a.z + a.w * a.w
          + b.x * b.x + b.y * b.y + b.z * b.z + b.w * b.w;
  uint4 p;
  p.x = ((unsigned)f2bf(a.y) << 16) | f2bf(a.x);
  p.y = ((unsigned)f2bf(a.w) << 16) | f2bf(a.z);
  p.z = ((unsigned)f2bf(b.y) << 16) | f2bf(b.x);
  p.w = ((unsigned)f2bf(b.w) << 16) | f2bf(b.z);
  *reinterpret_cast<uint4*>(CB + (size_t)k * Dd + t * 8) = p;
  #pragma unroll
  for (int m = 1; m < 64; m <<= 1) s += __shfl_xor(s, m, 64);
  if (t == 0) c2[k] = s;
}

// 512 threads (8 waves), 512 blocks, NT=4 tiles of 32 rows each.
// B: 128 VGPRs/wave, resident for the whole block (32 cols x 512 k, loaded once).
// A: 64KB fp32 tile via global_load_lds, double-buffered; counted vmcnt only.
// K-loop: barrier-free, global-load-free: ds_read + cvt + MFMA.
__global__ __launch_bounds__(512)
void cluster_q_kernel(const float* __restrict__ X,
                      const unsigned short* __restrict__ CB,
                      const float* __restrict__ c2g,
                      float* __restrict__ out) {
  __shared__ __align__(16) unsigned char Al[2][ATILE];   // 128 KB
  __shared__ float rowp[TROWS][8];
  __shared__ float rinvs[TROWS];

  const int tid  = threadIdx.x;
  const int lane = tid & 63;
  const int w    = tid >> 6;     // 0..7: wave owns cols [32w, 32w+32)
  const int hi   = lane >> 4;    // 0..3
  const int lo   = lane & 15;    // 0..15
  const int cb   = w * 32;

  // ---- Staging geometry: per instr i (0..7), wave w writes LDS chunks
  // (i*512 + w*64 + lane); chunk c holds row c>>7, stored col-chunk (cc ^ (row&7)).
  const int wh = w >> 1;
  const int cc = (w & 1) * 64 + lane;
  int off[8];                          // byte offset into X from tile base
  #pragma unroll
  for (int i = 0; i < 8; ++i) {
    const int row = i * 4 + wh;
    const int gch = cc ^ (row & 7);
    off[i] = (row * Dd + gch * 4) * 4;
  }

  // ---- B resident: bB[ks][n] = cols cb+n*16+lo, k = ks*32 + hi*8 .. +8.
  bf16x8 bB[16][2];
  #pragma unroll
  for (int ks = 0; ks < 16; ++ks)
    #pragma unroll
    for (int n = 0; n < 2; ++n)
      bB[ks][n] = *reinterpret_cast<const bf16x8*>(
          &CB[(size_t)(cb + n * 16 + lo) * Dd + ks * 32 + hi * 8]);
  float c2v[2];
  #pragma unroll
  for (int n = 0; n < 2; ++n) c2v[n] = c2g[cb + n * 16 + lo];
  fence();

  const float* xblk = X + (size_t)blockIdx.x * (NT * TROWS) * Dd;
  auto stage = [&](int t) {
    const char* xb = (const char*)(xblk + (size_t)t * TROWS * Dd);
    unsigned char* dbuf = Al[t & 1];
    #pragma unroll
    for (int i = 0; i < 8; ++i)
      gload16((const float*)(xb + off[i]), dbuf + (i * 512 + w * 64 + lane) * 16);
  };

  stage(0);
  fence();

  #pragma unroll 1
  for (int t = 0; t < NT; ++t) {
    // Issue next tile, then wait: 24 = 16 stores(t-1) + 8 stage(t+1) outstanding
    // allowed => stage(t) retired (in-order vmcnt). Store count is exactly 16
    // (scattered 4B stores, unmergeable). Never vmcnt(0) mid-loop.
    if (t < NT - 1) {
      stage(t + 1);
      fence();
      asm volatile("s_waitcnt vmcnt(24) lgkmcnt(0)" ::: "memory");
    } else {
      asm volatile("s_waitcnt vmcnt(16) lgkmcnt(0)" ::: "memory");
    }
    __builtin_amdgcn_s_barrier();
    fence();

    const unsigned char* base = Al[t & 1];
    f32x4 acc[2][2];
    #pragma unroll
    for (int m = 0; m < 2; ++m)
      #pragma unroll
      for (int n = 0; n < 2; ++n)
        #pragma unroll
        for (int r = 0; r < 4; ++r) acc[m][n][r] = 0.f;
    float x2p[2] = {0.f, 0.f};

    // Barrier-free K-loop: lane (lo,hi) reads A[row=m*16+lo][k=ks*32+hi*8..+8].
    #pragma unroll
    for (int ks = 0; ks < 16; ++ks) {
      bf16x8 af[2];
      #pragma unroll
      for (int m = 0; m < 2; ++m) {
        const int row = m * 16 + lo;
        const int s8  = row & 7;
        const int ch0 = (ks * 8 + hi * 2) ^ s8;
        const int ch1 = (ks * 8 + hi * 2 + 1) ^ s8;
        float4 q0 = *reinterpret_cast<const float4*>(base + row * 2048 + ch0 * 16);
        float4 q1 = *reinterpret_cast<const float4*>(base + row * 2048 + ch1 * 16);
        x2p[m] += q0.x * q0.x + q0.y * q0.y + q0.z * q0.z + q0.w * q0.w
                + q1.x * q1.x + q1.y * q1.y + q1.z * q1.z + q1.w * q1.w;
        af[m] = pack8(q0, q1);
      }
      #pragma unroll
      for (int m = 0; m < 2; ++m)
        #pragma unroll
        for (int n = 0; n < 2; ++n)
          acc[m][n] = __builtin_amdgcn_mfma_f32_16x16x32_bf16(af[m], bB[ks][n], acc[m][n], 0, 0, 0);
    }

    // x2 per row: sum the 4 hi-slices (each lane covered 128 of 512 k).
    float x2row[2];
    #pragma unroll
    for (int m = 0; m < 2; ++m) {
      float s = x2p[m];
      s += __shfl_xor(s, 16);
      s += __shfl_xor(s, 32);
      x2row[m] = s;                 // value for row m*16+lo (uniform over hi)
    }

    // q = 1/(1+dist); per-wave row partials over this wave's 32 cols.
    float rs[2][4] = {{0.f,0.f,0.f,0.f},{0.f,0.f,0.f,0.f}};
    #pragma unroll
    for (int m = 0; m < 2; ++m)
      #pragma unroll
      for (int r = 0; r < 4; ++r) {
        const float x2v = __shfl(x2row[m], hi * 4 + r);   // row m*16+hi*4+r
        #pragma unroll
        for (int n = 0; n < 2; ++n) {
          float dist = fmaxf(x2v + c2v[n] - 2.f * acc[m][n][r], 0.f);
          float qv = __builtin_amdgcn_rcpf(1.f + dist);
          acc[m][n][r] = qv;
          rs[m][r] += qv;
        }
      }

    #pragma unroll
    for (int m = 0; m < 2; ++m)
      #pragma unroll
      for (int r = 0; r < 4; ++r) {
        float s = rs[m][r];
        s += __shfl_xor(s, 1); s += __shfl_xor(s, 2);
        s += __shfl_xor(s, 4); s += __shfl_xor(s, 8);
        if (lo == 0) rowp[m * 16 + hi * 4 + r][w] = s;
      }
    rbar();                         // lgkm-only: staging stays in flight

    if (w == 0 && lane < TROWS) {
      float4 p0 = *reinterpret_cast<float4*>(&rowp[lane][0]);
      float4 p1 = *reinterpret_cast<float4*>(&rowp[lane][4]);
      rinvs[lane] = __builtin_amdgcn_rcpf(p0.x + p0.y + p0.z + p0.w
                                        + p1.x + p1.y + p1.z + p1.w);
    }
    rbar();

    const size_t r0g = (size_t)blockIdx.x * (NT * TROWS) + t * TROWS;
    #pragma unroll
    for (int m = 0; m < 2; ++m)
      #pragma unroll
      for (int r = 0; r < 4; ++r) {
        const int row = m * 16 + hi * 4 + r;
        const float ri = rinvs[row];
        #pragma unroll
        for (int n = 0; n < 2; ++n)
          out[(r0g + row) * Kk + cb + n * 16 + lo] = acc[m][n][r] * ri;  // 16 x 4B stores
      }
    fence();
  }
}

extern "C" void kernel_launch(void* const* d_in, const int* in_sizes, int n_in,
                              void* d_out, int out_size, void* d_ws, size_t ws_size,
                              hipStream_t stream) {
  const float* X = reinterpret_cast<const float*>(d_in[0]);
  const float* C = reinterpret_cast<const float*>(d_in[1]);
  unsigned short* CB = reinterpret_cast<unsigned short*>(d_ws);           // 256 KB bf16 clusters
  float* c2 = reinterpret_cast<float*>(reinterpret_cast<char*>(d_ws) + (size_t)Kk * Dd * 2);
  prep_clusters_kernel<<<Kk, 64, 0, stream>>>(C, CB, c2);
  cluster_q_kernel<<<Nn / (NT * TROWS), 512, 0, stream>>>(X, CB, c2, reinterpret_cast<float*>(d_out));
}

// Round 9
// 69.413 us; speedup vs baseline: 1.6694x; 1.2743x over previous
//
#include <hip/hip_runtime.h>
#include <hip/hip_bf16.h>

typedef short bf16x8 __attribute__((ext_vector_type(8)));
typedef float f32x4 __attribute__((ext_vector_type(4)));

constexpr int Nn = 65536;
constexpr int Kk = 256;
constexpr int Dd = 512;
constexpr int BM = 64;
constexpr int BK = 64;

static __device__ __forceinline__ unsigned short f2bf(float f) {
  __hip_bfloat16 h = __float2bfloat16(f);
  return *reinterpret_cast<unsigned short*>(&h);
}

static __device__ __forceinline__ void fence() { asm volatile("" ::: "memory"); }

// LDS-visibility-only barrier: vmcnt NOT drained (in-flight prefetches survive).
static __device__ __forceinline__ void rbar() {
  asm volatile("s_waitcnt lgkmcnt(0)" ::: "memory");
  __builtin_amdgcn_s_barrier();
  fence();
}

// Convert clusters to bf16 (row-major [K][D]) and compute c2[k] = sum_d c[k][d]^2 in fp32.
__global__ __launch_bounds__(64)
void prep_clusters_kernel(const float* __restrict__ C,
                          unsigned short* __restrict__ CB,
                          float* __restrict__ c2) {
  const int k = blockIdx.x;
  const int t = threadIdx.x;
  const float* row = C + (size_t)k * Dd;
  float4 a = *reinterpret_cast<const float4*>(row + t * 8);
  float4 b = *reinterpret_cast<const float4*>(row + t * 8 + 4);
  float s = a.x * a.x + a.y * a.y + a.z * a.z + a.w * a.w
          + b.x * b.x + b.y * b.y + b.z * b.z + b.w * b.w;
  uint4 p;
  p.x = ((unsigned)f2bf(a.y) << 16) | f2bf(a.x);
  p.y = ((unsigned)f2bf(a.w) << 16) | f2bf(a.z);
  p.z = ((unsigned)f2bf(b.y) << 16) | f2bf(b.x);
  p.w = ((unsigned)f2bf(b.w) << 16) | f2bf(b.z);
  *reinterpret_cast<uint4*>(CB + (size_t)k * Dd + t * 8) = p;
  #pragma unroll
  for (int m = 1; m < 64; m <<= 1) s += __shfl_xor(s, m, 64);
  if (t == 0) c2[k] = s;
}

// R3 structure (best: 61.8us) + two fixes:
//  (a) A-prefetch depth 3 (v[3]): loadG(k) is ~2.2 iters old when stage(k) consumes it
//      -> ~900cy HBM latency covered (depth 2 left ~300cy/iter residual stall).
//  (b) B issued FIRST each iter: compute(ks)'s bB wait drains only >=2-iter-old loads;
//      G(ks+2), B(ks+1), G(ks+3) stay in flight across the barrier (in-order vmcnt).
__global__ __launch_bounds__(256, 2)
void cluster_q_kernel(const float* __restrict__ X,
                      const unsigned short* __restrict__ CB,
                      const float* __restrict__ c2g,
                      float* __restrict__ out) {
  __shared__ __align__(16) char Al[2][BM * BK * 2];  // swizzled bf16 A tiles, 8KB each
  __shared__ float x2s[BM];
  __shared__ __align__(16) float rowp[BM][4];        // per-wave row partial sums

  const int tid  = threadIdx.x;
  const int lane = tid & 63;
  const int wave = tid >> 6;
  const int hi   = lane >> 4;   // 0..3
  const int lo   = lane & 15;   // 0..15
  const int rbase = blockIdx.x * BM;
  const int arow  = tid >> 4;          // 0..15: staging row group
  const int acolb = (tid & 15) * 8;    // staging byte offset within LDS row (4 bf16)

  f32x4 acc[4][4];
  #pragma unroll
  for (int m = 0; m < 4; ++m)
    #pragma unroll
    for (int n = 0; n < 4; ++n)
      #pragma unroll
      for (int r = 0; r < 4; ++r) acc[m][n][r] = 0.f;

  float x2p[4] = {0.f, 0.f, 0.f, 0.f};
  float4 v[3][4];               // A reg-prefetch, 3 deep (static idx via full unroll)
  bf16x8 bA[4][2], bB[4][2];

  auto loadG = [&](int ks) {
    #pragma unroll
    for (int it = 0; it < 4; ++it)
      v[ks % 3][it] = *reinterpret_cast<const float4*>(
          &X[(size_t)(rbase + it * 16 + arow) * Dd + ks * BK + (tid & 15) * 4]);
  };

  auto stage = [&](int ks) {
    #pragma unroll
    for (int it = 0; it < 4; ++it) {
      const int row = it * 16 + arow;
      float4 f = v[ks % 3][it];
      x2p[it] += f.x * f.x + f.y * f.y + f.z * f.z + f.w * f.w;
      uint2 p;
      p.x = ((unsigned)f2bf(f.y) << 16) | f2bf(f.x);
      p.y = ((unsigned)f2bf(f.w) << 16) | f2bf(f.z);
      const int addr = (row * 128 + acolb) ^ ((row & 7) << 4);  // XOR-swizzle (G4)
      *reinterpret_cast<uint2*>(&Al[ks & 1][addr]) = p;
    }
  };

  auto loadB = [&](int ks, bf16x8 (&bf)[4][2]) {
    #pragma unroll
    for (int n = 0; n < 4; ++n)
      #pragma unroll
      for (int ku = 0; ku < 2; ++ku)
        bf[n][ku] = *reinterpret_cast<const bf16x8*>(
            &CB[(size_t)(wave * 64 + n * 16 + lo) * Dd + ks * BK + ku * 32 + hi * 8]);
  };

  auto compute = [&](int ks, bf16x8 (&bf)[4][2]) {
    #pragma unroll
    for (int ku = 0; ku < 2; ++ku) {
      bf16x8 af[4];
      #pragma unroll
      for (int m = 0; m < 4; ++m) {
        const int row = m * 16 + lo;
        const int addr = (row * 128 + ku * 64 + hi * 16) ^ ((row & 7) << 4);
        af[m] = *reinterpret_cast<const bf16x8*>(&Al[ks & 1][addr]);
      }
      #pragma unroll
      for (int m = 0; m < 4; ++m)
        #pragma unroll
        for (int n = 0; n < 4; ++n)
          acc[m][n] = __builtin_amdgcn_mfma_f32_16x16x32_bf16(af[m], bf[n][ku], acc[m][n], 0, 0, 0);
    }
  };

  // Prologue: 3 A-tiles + B(0) in flight; stage(0) blocks only on G(0) (oldest).
  loadG(0); fence();
  loadG(1); fence();
  loadG(2); fence();
  loadB(0, bA); fence();
  stage(0);
  rbar();

  auto iter = [&](int ks, bf16x8 (&bcur)[4][2], bf16x8 (&bnxt)[4][2]) {
    if (ks < 7) { loadB(ks + 1, bnxt); fence(); }  // B first: decoupled from A drains
    if (ks < 7) { stage(ks + 1); fence(); }        // consumes G(ks+1), issued 2-3 iters ago
    if (ks < 5) { loadG(ks + 3); fence(); }        // deep A prefetch into v[ks%3]
    compute(ks, bcur);
    rbar();                                        // lgkm-only barrier
  };

  #pragma unroll
  for (int p = 0; p < 4; ++p) {
    iter(2 * p, bA, bB);
    iter(2 * p + 1, bB, bA);
  }

  // Finalize x2 (row sums of squares, fp32-exact): reduce across the 16 threads per row.
  #pragma unroll
  for (int it = 0; it < 4; ++it) {
    float s = x2p[it];
    s += __shfl_xor(s, 1); s += __shfl_xor(s, 2);
    s += __shfl_xor(s, 4); s += __shfl_xor(s, 8);
    if ((tid & 15) == 0) x2s[it * 16 + arow] = s;
  }
  __syncthreads();

  float c2v[4];
  #pragma unroll
  for (int n = 0; n < 4; ++n) c2v[n] = c2g[wave * 64 + n * 16 + lo];

  // dist -> q = 1/(1+dist) (ALPHA=1 => exponent 1); v_rcp_f32 ~1ulp, err << threshold.
  float rs[4][4];
  #pragma unroll
  for (int m = 0; m < 4; ++m)
    #pragma unroll
    for (int r = 0; r < 4; ++r) rs[m][r] = 0.f;

  #pragma unroll
  for (int m = 0; m < 4; ++m) {
    #pragma unroll
    for (int n = 0; n < 4; ++n) {
      #pragma unroll
      for (int r = 0; r < 4; ++r) {
        const int row = m * 16 + hi * 4 + r;  // C/D: col=lane&15, row=(lane>>4)*4+reg
        float dist = x2s[row] + c2v[n] - 2.f * acc[m][n][r];
        dist = fmaxf(dist, 0.f);
        float qv = __builtin_amdgcn_rcpf(1.f + dist);
        acc[m][n][r] = qv;
        rs[m][r] += qv;
      }
    }
  }

  // Reduce row sums across the 16 cols held per lane-group, then across 4 waves via LDS.
  #pragma unroll
  for (int m = 0; m < 4; ++m)
    #pragma unroll
    for (int r = 0; r < 4; ++r) {
      float s = rs[m][r];
      s += __shfl_xor(s, 1); s += __shfl_xor(s, 2);
      s += __shfl_xor(s, 4); s += __shfl_xor(s, 8);
      rs[m][r] = s;
    }

  if (lo == 0) {
    #pragma unroll
    for (int m = 0; m < 4; ++m)
      #pragma unroll
      for (int r = 0; r < 4; ++r)
        rowp[m * 16 + hi * 4 + r][wave] = rs[m][r];
  }
  __syncthreads();

  float rinv[4][4];
  #pragma unroll
  for (int m = 0; m < 4; ++m)
    #pragma unroll
    for (int r = 0; r < 4; ++r) {
      float4 t = *reinterpret_cast<float4*>(rowp[m * 16 + hi * 4 + r]);
      rinv[m][r] = __builtin_amdgcn_rcpf(t.x + t.y + t.z + t.w);
    }

  #pragma unroll
  for (int m = 0; m < 4; ++m)
    #pragma unroll
    for (int n = 0; n < 4; ++n)
      #pragma unroll
      for (int r = 0; r < 4; ++r) {
        const int row = m * 16 + hi * 4 + r;
        out[(size_t)(rbase + row) * Kk + wave * 64 + n * 16 + lo] = acc[m][n][r] * rinv[m][r];
      }
}

extern "C" void kernel_launch(void* const* d_in, const int* in_sizes, int n_in,
                              void* d_out, int out_size, void* d_ws, size_t ws_size,
                              hipStream_t stream) {
  const float* X = reinterpret_cast<const float*>(d_in[0]);
  const float* C = reinterpret_cast<const float*>(d_in[1]);
  unsigned short* CB = reinterpret_cast<unsigned short*>(d_ws);           // 256 KB bf16 clusters
  float* c2 = reinterpret_cast<float*>(reinterpret_cast<char*>(d_ws) + (size_t)Kk * Dd * 2);
  prep_clusters_kernel<<<Kk, 64, 0, stream>>>(C, CB, c2);
  cluster_q_kernel<<<Nn / BM, 256, 0, stream>>>(X, CB, c2, reinterpret_cast<float*>(d_out));
}